// Round 6
// baseline (70.324 us; speedup 1.0000x reference)
//
#include <hip/hip_runtime.h>
#include <hip/hip_bf16.h>

typedef unsigned short u16;
typedef unsigned int u32;
typedef __attribute__((ext_vector_type(8))) short bf16x8;
typedef __attribute__((ext_vector_type(16))) float f32x16;

#define S_LEN 2048
#define NHQ   16
#define NHKV  4
#define HD    64
#define KVBLK 64
#define QBLK  256
#define LPAD  72          // 144B row stride
#define KVSTR (NHKV*HD)   // 256
#define QSTR  (NHQ*HD)    // 1024
// (1/sqrt(64)) * log2(e): scores land in exp2 domain
#define QSCALE 0.18033688011112042f
#define DEFER_THR 8.0f

__device__ __forceinline__ u32 cvt2(float lo, float hi) {
    __hip_bfloat162 hh = __float22bfloat162_rn(make_float2(lo, hi));
    union { __hip_bfloat162 h; u32 u; } c; c.h = hh; return c.u;   // v_cvt_pk_bf16_f32
}
__device__ __forceinline__ u16 cvt1(float x) {
    __hip_bfloat16 hh = __float2bfloat16(x);
    union { __hip_bfloat16 h; u16 u; } c; c.h = hh; return c.u;
}

__global__ __launch_bounds__(512, 2)
void gqa_fwd_kernel(const float* __restrict__ Qp, const float* __restrict__ Kp,
                    const float* __restrict__ Vp, float* __restrict__ Op)
{
    __shared__ __align__(16) u16 Kl[2][KVBLK][LPAD];  // K dbuf, [kv][d]
    __shared__ __align__(16) u16 Vt[2][HD][LPAD];     // V dbuf, transposed [dv][kv]

    const int tid  = threadIdx.x;
    const int w    = tid >> 6;
    const int lane = tid & 63;
    const int q31  = lane & 31;
    const int h    = lane >> 5;        // lane half

    // grid: 256 blocks, 1/CU. bid&7 spans (kvh,b) -> XCD L2 stream locality.
    // qt = 7 - (bid>>5): diagonal (heaviest) blocks dispatch first.
    const int bid  = blockIdx.x;
    const int head = bid & 31;
    const int qt   = 7 - (bid >> 5);
    const int kvh  = head & 3;
    const int b    = (head >> 2) & 1;
    const int qh   = kvh * 4 + (head >> 3);

    const float* Kbase = Kp + (size_t)b * S_LEN * KVSTR + kvh*HD;
    const float* Vbase = Vp + (size_t)b * S_LEN * KVSTR + kvh*HD;
    const int    qrow  = qt*QBLK + w*32 + q31;          // this lane's q row
    const float* qp    = Qp + ((size_t)b * S_LEN + qrow) * QSTR + qh*HD;
    float*       ob    = Op + ((size_t)(b*NHQ + qh) * S_LEN + qrow) * HD;

    const int nt    = 4*qt + 3;          // kv tiles 0..nt
    const int tlast = 4*qt + (w >> 1);   // this wave's diagonal tile
    const int qcmp  = q31 + 32*(w & 1);  // mask kvl > qcmp at t==tlast

    // staging maps (512 threads, one 64x64 tile each of K and V):
    // K row-major b128 stores; V transposed contiguous scalar b16 stores.
    const int krow = tid >> 3;           // 0..63
    const int kd   = (tid & 7) * 8;      // 0..56
    const int vrow = tid & 63;           // kv
    const int vd0  = w * 8;              // 0..56

    // ---- Q fragments (B operand of swapped QK^T): B[k=ks*16+h*8+i][q=q31] ----
    bf16x8 qf[4];
    #pragma unroll
    for (int ks = 0; ks < 4; ++ks) {
        const int d = ks*16 + h*8;
        const float4 x = *(const float4*)(qp + d);
        const float4 y = *(const float4*)(qp + d + 4);
        union { u32 u[4]; bf16x8 v; } t;
        t.u[0] = cvt2(x.x*QSCALE, x.y*QSCALE);
        t.u[1] = cvt2(x.z*QSCALE, x.w*QSCALE);
        t.u[2] = cvt2(y.x*QSCALE, y.y*QSCALE);
        t.u[3] = cvt2(y.z*QSCALE, y.w*QSCALE);
        qf[ks] = t.v;
    }

    // O^T accumulators: oacc{0,1}[rg] = O[q=q31][dv = set*32 + (rg&3)+8*(rg>>2)+4h]
    f32x16 oacc0, oacc1;
    #pragma unroll
    for (int i = 0; i < 16; ++i) { oacc0[i] = 0.f; oacc1[i] = 0.f; }
    float m_s = -1e30f;   // running max for q row (synced across lane halves)
    float l_p = 0.f;      // per-half partial row-sum; reduced in epilogue

    // ---- prologue: stage tile 0 into buf 0 ----
    {
        const float4 kx = *(const float4*)(Kbase + (size_t)krow*KVSTR + kd);
        const float4 ky = *(const float4*)(Kbase + (size_t)krow*KVSTR + kd + 4);
        *(uint4*)(&Kl[0][krow][kd]) = make_uint4(
            cvt2(kx.x,kx.y), cvt2(kx.z,kx.w), cvt2(ky.x,ky.y), cvt2(ky.z,ky.w));
        const float4 vx = *(const float4*)(Vbase + (size_t)vrow*KVSTR + vd0);
        const float4 vy = *(const float4*)(Vbase + (size_t)vrow*KVSTR + vd0 + 4);
        Vt[0][vd0+0][vrow] = cvt1(vx.x); Vt[0][vd0+1][vrow] = cvt1(vx.y);
        Vt[0][vd0+2][vrow] = cvt1(vx.z); Vt[0][vd0+3][vrow] = cvt1(vx.w);
        Vt[0][vd0+4][vrow] = cvt1(vy.x); Vt[0][vd0+5][vrow] = cvt1(vy.y);
        Vt[0][vd0+6][vrow] = cvt1(vy.z); Vt[0][vd0+7][vrow] = cvt1(vy.w);
    }
    __syncthreads();

    const float* kpt = Kbase + (size_t)(KVBLK + krow)*KVSTR + kd;
    const float* vpt = Vbase + (size_t)(KVBLK + vrow)*KVSTR + vd0;
    int cur = 0;

    for (int t = 0; t <= nt; ++t) {
        const bool pf_on = (t < nt);

        // ---- issue global prefetch for tile t+1 (consumed after compute) ----
        float4 kpf0, kpf1, vpf0, vpf1;
        if (pf_on) {
            kpf0 = *(const float4*)(kpt);
            kpf1 = *(const float4*)(kpt + 4);
            vpf0 = *(const float4*)(vpt);
            vpf1 = *(const float4*)(vpt + 4);
        }

        if (t <= tlast) {
            // ---- swapped QK^T (32x32x16): s{set}[rg] = S[kv=set*32+(rg&3)+8*(rg>>2)+4h][q=q31]
            f32x16 s0, s1;
            #pragma unroll
            for (int i = 0; i < 16; ++i) { s0[i] = 0.f; s1[i] = 0.f; }
            __builtin_amdgcn_s_setprio(1);
            #pragma unroll
            for (int ks = 0; ks < 4; ++ks) {
                bf16x8 k0 = *(const bf16x8*)(&Kl[cur][q31][ks*16 + h*8]);
                bf16x8 k1 = *(const bf16x8*)(&Kl[cur][32 + q31][ks*16 + h*8]);
                s0 = __builtin_amdgcn_mfma_f32_32x32x16_bf16(k0, qf[ks], s0, 0, 0, 0);
                s1 = __builtin_amdgcn_mfma_f32_32x32x16_bf16(k1, qf[ks], s1, 0, 0, 0);
            }
            __builtin_amdgcn_s_setprio(0);

            // ---- causal mask on this wave's diagonal tile ----
            if (t == tlast) {
                #pragma unroll
                for (int rg = 0; rg < 16; ++rg) {
                    const int kvl = (rg & 3) + 8*(rg >> 2) + 4*h;
                    if (kvl > qcmp)      s0[rg] = -1e30f;
                    if (kvl + 32 > qcmp) s1[rg] = -1e30f;
                }
            }

            // ---- local max over the lane's 32 scores (tree) ----
            float mx[8];
            #pragma unroll
            for (int i = 0; i < 8; ++i)
                mx[i] = fmaxf(fmaxf(s0[i], s0[i+8]), fmaxf(s1[i], s1[i+8]));
            const float lmax = fmaxf(fmaxf(fmaxf(mx[0],mx[1]), fmaxf(mx[2],mx[3])),
                                     fmaxf(fmaxf(mx[4],mx[5]), fmaxf(mx[6],mx[7])));

            // ---- T13 defer-max: reduce+rescale only when the max grew ----
            if (!__all(lmax <= m_s + DEFER_THR)) {
                float rmax = fmaxf(lmax, __shfl_xor(lmax, 32));
                const float mnew = fmaxf(m_s, rmax);
                const float cf   = __builtin_amdgcn_exp2f(m_s - mnew);
                m_s = mnew;
                l_p *= cf;
                #pragma unroll
                for (int i = 0; i < 16; ++i) { oacc0[i] *= cf; oacc1[i] *= cf; }
            }

            // ---- exp2 + partial sums ----
            float ps0 = 0.f, ps1 = 0.f;
            #pragma unroll
            for (int rg = 0; rg < 16; ++rg) {
                const float p0 = __builtin_amdgcn_exp2f(s0[rg] - m_s);
                const float p1 = __builtin_amdgcn_exp2f(s1[rg] - m_s);
                s0[rg] = p0; ps0 += p0;
                s1[rg] = p1; ps1 += p1;
            }
            l_p += ps0 + ps1;

            // ---- T12: P -> B-operand entirely in registers ----
            // packs: A[m]=pk(p[kv=8m+4h'+0,1]), B[m]=pk(p[.. +2,3]) for m=0..7
            u32 Aw[8], Bw[8];
            #pragma unroll
            for (int m = 0; m < 4; ++m) {
                Aw[m]   = cvt2(s0[m*4+0], s0[m*4+1]);
                Bw[m]   = cvt2(s0[m*4+2], s0[m*4+3]);
                Aw[4+m] = cvt2(s1[m*4+0], s1[m*4+1]);
                Bw[4+m] = cvt2(s1[m*4+2], s1[m*4+3]);
            }

            // ---- O^T += V^T P : per c, frag words via permlane32_swap ----
            __builtin_amdgcn_s_setprio(1);
            #pragma unroll
            for (int c = 0; c < 4; ++c) {
                u32 w0 = Aw[2*c], w2 = Aw[2*c+1];
                u32 w1 = Bw[2*c], w3 = Bw[2*c+1];
                asm("v_permlane32_swap_b32 %0, %1" : "+v"(w0), "+v"(w2));
                asm("v_permlane32_swap_b32 %0, %1" : "+v"(w1), "+v"(w3));
                union { u32 u[4]; bf16x8 v; } pu;
                pu.u[0] = w0; pu.u[1] = w1; pu.u[2] = w2; pu.u[3] = w3;
                bf16x8 v0 = *(const bf16x8*)(&Vt[cur][q31][c*16 + h*8]);
                bf16x8 v1 = *(const bf16x8*)(&Vt[cur][32 + q31][c*16 + h*8]);
                oacc0 = __builtin_amdgcn_mfma_f32_32x32x16_bf16(v0, pu.v, oacc0, 0, 0, 0);
                oacc1 = __builtin_amdgcn_mfma_f32_32x32x16_bf16(v1, pu.v, oacc1, 0, 0, 0);
            }
            __builtin_amdgcn_s_setprio(0);
        }

        // ---- write prefetched tile to the other buffer; one barrier/tile ----
        if (pf_on) {
            *(uint4*)(&Kl[cur^1][krow][kd]) = make_uint4(
                cvt2(kpf0.x,kpf0.y), cvt2(kpf0.z,kpf0.w),
                cvt2(kpf1.x,kpf1.y), cvt2(kpf1.z,kpf1.w));
            Vt[cur^1][vd0+0][vrow] = cvt1(vpf0.x); Vt[cur^1][vd0+1][vrow] = cvt1(vpf0.y);
            Vt[cur^1][vd0+2][vrow] = cvt1(vpf0.z); Vt[cur^1][vd0+3][vrow] = cvt1(vpf0.w);
            Vt[cur^1][vd0+4][vrow] = cvt1(vpf1.x); Vt[cur^1][vd0+5][vrow] = cvt1(vpf1.y);
            Vt[cur^1][vd0+6][vrow] = cvt1(vpf1.z); Vt[cur^1][vd0+7][vrow] = cvt1(vpf1.w);
            kpt += (size_t)KVBLK * KVSTR;
            vpt += (size_t)KVBLK * KVSTR;
            __syncthreads();
            cur ^= 1;
        }
    }

    // ---- epilogue: combine halves' l, normalize, store O^T (float4) ----
    l_p += __shfl_xor(l_p, 32);
    const float inv = 1.0f / l_p;
    #pragma unroll
    for (int k = 0; k < 4; ++k) {
        float4 o;
        o.x = oacc0[4*k+0]*inv; o.y = oacc0[4*k+1]*inv;
        o.z = oacc0[4*k+2]*inv; o.w = oacc0[4*k+3]*inv;
        *(float4*)(ob + 8*k + 4*h) = o;
        o.x = oacc1[4*k+0]*inv; o.y = oacc1[4*k+1]*inv;
        o.z = oacc1[4*k+2]*inv; o.w = oacc1[4*k+3]*inv;
        *(float4*)(ob + 32 + 8*k + 4*h) = o;
    }
}

extern "C" void kernel_launch(void* const* d_in, const int* in_sizes, int n_in,
                              void* d_out, int out_size, void* d_ws, size_t ws_size,
                              hipStream_t stream) {
    const float* Q = (const float*)d_in[0];
    const float* K = (const float*)d_in[1];
    const float* V = (const float*)d_in[2];
    // d_in[3] (tril mask) computed analytically, never read.
    float* O = (float*)d_out;
    gqa_fwd_kernel<<<dim3(256), dim3(512), 0, stream>>>(Q, K, V, O);
}

// Round 7
// 62.664 us; speedup vs baseline: 1.1222x; 1.1222x over previous
//
#include <hip/hip_runtime.h>
#include <hip/hip_bf16.h>

typedef unsigned short u16;
typedef unsigned int u32;
typedef __attribute__((ext_vector_type(8))) short bf16x8;
typedef __attribute__((ext_vector_type(16))) float f32x16;

#define S_LEN 2048
#define NHQ   16
#define NHKV  4
#define HD    64
#define KVBLK 64
#define LPAD  72          // 144B row stride
#define KVSTR (NHKV*HD)   // 256
#define QSTR  (NHQ*HD)    // 1024
// (1/sqrt(64)) * log2(e): scores land in exp2 domain
#define QSCALE 0.18033688011112042f
#define DEFER_THR 8.0f

__device__ __forceinline__ u32 cvt2(float lo, float hi) {
    __hip_bfloat162 hh = __float22bfloat162_rn(make_float2(lo, hi));
    union { __hip_bfloat162 h; u32 u; } c; c.h = hh; return c.u;   // v_cvt_pk_bf16_f32
}
__device__ __forceinline__ u16 cvt1(float x) {
    __hip_bfloat16 hh = __float2bfloat16(x);
    union { __hip_bfloat16 h; u16 u; } c; c.h = hh; return c.u;
}

__global__ __launch_bounds__(512, 2)
void gqa_fwd_kernel(const float* __restrict__ Qp, const float* __restrict__ Kp,
                    const float* __restrict__ Vp, float* __restrict__ Op)
{
    __shared__ __align__(16) u16 Kl[2][KVBLK][LPAD];  // K dbuf, [kv][d]
    __shared__ __align__(16) u16 Vt[2][HD][LPAD];     // V dbuf, transposed [dv][kv]

    const int tid  = threadIdx.x;
    const int w    = tid >> 6;
    const int lane = tid & 63;
    const int q31  = lane & 31;
    const int h    = lane >> 5;        // lane half

    // 256 blocks, 1/CU. head = bid&31 (bid&7 spans (kvh,b) -> XCD L2 streams).
    // j = bid>>5: block owns q-tiles hi=(15-j)*128 (waves {0,3,5,6}) and
    // lo=j*128 (waves {1,2,4,7}); popcount-parity split puts one hi + one lo
    // wave on each SIMD under either i%4 or i/2 wave->SIMD mapping ->
    // per-SIMD compute uniform (34-36 wave-tile-visits) for ALL blocks.
    const int bid  = blockIdx.x;
    const int head = bid & 31;
    const int j    = bid >> 5;
    const int kvh  = head & 3;
    const int b    = (head >> 2) & 1;
    const int qh   = kvh * 4 + (head >> 3);

    const int qhi   = 15 - j;
    const int qlo   = j;
    const int par   = __popc(w) & 1;           // 0 -> hi group
    const int qt_w  = par ? qlo : qhi;
    const int qbase = qt_w * 128 + (w >> 1) * 32;   // w>>1 is unique 0..3 in each group
    const int nt    = 2*qhi + 1;               // staged kv tiles 0..nt
    const int tlast = 2*qt_w + (w >> 2);       // this wave's diagonal tile
    const int qcmp  = q31 + 32*((w >> 1) & 1); // mask kvl > qcmp at t==tlast
    const int qrow  = qbase + q31;             // lane's global q row

    const float* Kbase = Kp + (size_t)b * S_LEN * KVSTR + kvh*HD;
    const float* Vbase = Vp + (size_t)b * S_LEN * KVSTR + kvh*HD;
    const float* qp    = Qp + ((size_t)b * S_LEN + qrow) * QSTR + qh*HD;
    float*       ob    = Op + ((size_t)(b*NHQ + qh) * S_LEN + qrow) * HD;

    // staging maps (512 threads, one 64x64 tile each of K and V):
    // K row-major b128 stores; V transposed contiguous scalar b16 stores.
    const int krow = tid >> 3;           // 0..63
    const int kd   = (tid & 7) * 8;      // 0..56
    const int vrow = tid & 63;           // kv
    const int vd0  = w * 8;              // 0..56

    // ---- Q fragments (B operand of swapped QK^T): B[k=ks*16+h*8+i][q=q31] ----
    bf16x8 qf[4];
    #pragma unroll
    for (int ks = 0; ks < 4; ++ks) {
        const int d = ks*16 + h*8;
        const float4 x = *(const float4*)(qp + d);
        const float4 y = *(const float4*)(qp + d + 4);
        union { u32 u[4]; bf16x8 v; } t;
        t.u[0] = cvt2(x.x*QSCALE, x.y*QSCALE);
        t.u[1] = cvt2(x.z*QSCALE, x.w*QSCALE);
        t.u[2] = cvt2(y.x*QSCALE, y.y*QSCALE);
        t.u[3] = cvt2(y.z*QSCALE, y.w*QSCALE);
        qf[ks] = t.v;
    }

    // O^T accumulators: oacc{0,1}[rg] = O[q=q31][dv = set*32 + (rg&3)+8*(rg>>2)+4h]
    f32x16 oacc0, oacc1;
    #pragma unroll
    for (int i = 0; i < 16; ++i) { oacc0[i] = 0.f; oacc1[i] = 0.f; }
    float m_s = -1e30f;   // running max for q row (synced across lane halves)
    float l_p = 0.f;      // per-half partial row-sum; reduced in epilogue

    // ---- prologue: stage tile 0 into buf 0 ----
    {
        const float4 kx = *(const float4*)(Kbase + (size_t)krow*KVSTR + kd);
        const float4 ky = *(const float4*)(Kbase + (size_t)krow*KVSTR + kd + 4);
        *(uint4*)(&Kl[0][krow][kd]) = make_uint4(
            cvt2(kx.x,kx.y), cvt2(kx.z,kx.w), cvt2(ky.x,ky.y), cvt2(ky.z,ky.w));
        const float4 vx = *(const float4*)(Vbase + (size_t)vrow*KVSTR + vd0);
        const float4 vy = *(const float4*)(Vbase + (size_t)vrow*KVSTR + vd0 + 4);
        Vt[0][vd0+0][vrow] = cvt1(vx.x); Vt[0][vd0+1][vrow] = cvt1(vx.y);
        Vt[0][vd0+2][vrow] = cvt1(vx.z); Vt[0][vd0+3][vrow] = cvt1(vx.w);
        Vt[0][vd0+4][vrow] = cvt1(vy.x); Vt[0][vd0+5][vrow] = cvt1(vy.y);
        Vt[0][vd0+6][vrow] = cvt1(vy.z); Vt[0][vd0+7][vrow] = cvt1(vy.w);
    }
    __syncthreads();

    const float* kpt = Kbase + (size_t)(KVBLK + krow)*KVSTR + kd;
    const float* vpt = Vbase + (size_t)(KVBLK + vrow)*KVSTR + vd0;
    int cur = 0;

    for (int t = 0; t <= nt; ++t) {
        const bool pf_on = (t < nt);

        // ---- issue global prefetch for tile t+1 (consumed after compute) ----
        float4 kpf0, kpf1, vpf0, vpf1;
        if (pf_on) {
            kpf0 = *(const float4*)(kpt);
            kpf1 = *(const float4*)(kpt + 4);
            vpf0 = *(const float4*)(vpt);
            vpf1 = *(const float4*)(vpt + 4);
        }
        // pin the prefetch issue point: loads may not sink past this into the
        // staging-write section (which would expose full memory latency serially)
        asm volatile("" ::: "memory");

        if (t <= tlast) {
            // ---- swapped QK^T (32x32x16): s{set}[rg] = S[kv=set*32+(rg&3)+8*(rg>>2)+4h][q=q31]
            f32x16 s0, s1;
            #pragma unroll
            for (int i = 0; i < 16; ++i) { s0[i] = 0.f; s1[i] = 0.f; }
            __builtin_amdgcn_s_setprio(1);
            #pragma unroll
            for (int ks = 0; ks < 4; ++ks) {
                bf16x8 k0 = *(const bf16x8*)(&Kl[cur][q31][ks*16 + h*8]);
                bf16x8 k1 = *(const bf16x8*)(&Kl[cur][32 + q31][ks*16 + h*8]);
                s0 = __builtin_amdgcn_mfma_f32_32x32x16_bf16(k0, qf[ks], s0, 0, 0, 0);
                s1 = __builtin_amdgcn_mfma_f32_32x32x16_bf16(k1, qf[ks], s1, 0, 0, 0);
            }
            __builtin_amdgcn_s_setprio(0);

            // ---- causal mask on this wave's diagonal tile ----
            if (t == tlast) {
                #pragma unroll
                for (int rg = 0; rg < 16; ++rg) {
                    const int kvl = (rg & 3) + 8*(rg >> 2) + 4*h;
                    if (kvl > qcmp)      s0[rg] = -1e30f;
                    if (kvl + 32 > qcmp) s1[rg] = -1e30f;
                }
            }

            // ---- local max over the lane's 32 scores (tree) ----
            float mx[8];
            #pragma unroll
            for (int i = 0; i < 8; ++i)
                mx[i] = fmaxf(fmaxf(s0[i], s0[i+8]), fmaxf(s1[i], s1[i+8]));
            const float lmax = fmaxf(fmaxf(fmaxf(mx[0],mx[1]), fmaxf(mx[2],mx[3])),
                                     fmaxf(fmaxf(mx[4],mx[5]), fmaxf(mx[6],mx[7])));

            // ---- T13 defer-max: reduce+rescale only when the max grew ----
            if (!__all(lmax <= m_s + DEFER_THR)) {
                float rmax = fmaxf(lmax, __shfl_xor(lmax, 32));
                const float mnew = fmaxf(m_s, rmax);
                const float cf   = __builtin_amdgcn_exp2f(m_s - mnew);
                m_s = mnew;
                l_p *= cf;
                #pragma unroll
                for (int i = 0; i < 16; ++i) { oacc0[i] *= cf; oacc1[i] *= cf; }
            }

            // ---- exp2 + partial sums ----
            float ps0 = 0.f, ps1 = 0.f;
            #pragma unroll
            for (int rg = 0; rg < 16; ++rg) {
                const float p0 = __builtin_amdgcn_exp2f(s0[rg] - m_s);
                const float p1 = __builtin_amdgcn_exp2f(s1[rg] - m_s);
                s0[rg] = p0; ps0 += p0;
                s1[rg] = p1; ps1 += p1;
            }
            l_p += ps0 + ps1;

            // ---- T12: P -> B-operand entirely in registers ----
            u32 Aw[8], Bw[8];
            #pragma unroll
            for (int m = 0; m < 4; ++m) {
                Aw[m]   = cvt2(s0[m*4+0], s0[m*4+1]);
                Bw[m]   = cvt2(s0[m*4+2], s0[m*4+3]);
                Aw[4+m] = cvt2(s1[m*4+0], s1[m*4+1]);
                Bw[4+m] = cvt2(s1[m*4+2], s1[m*4+3]);
            }

            // ---- O^T += V^T P : per c, frag words via permlane32_swap ----
            __builtin_amdgcn_s_setprio(1);
            #pragma unroll
            for (int c = 0; c < 4; ++c) {
                u32 w0 = Aw[2*c], w2 = Aw[2*c+1];
                u32 w1 = Bw[2*c], w3 = Bw[2*c+1];
                asm("v_permlane32_swap_b32 %0, %1" : "+v"(w0), "+v"(w2));
                asm("v_permlane32_swap_b32 %0, %1" : "+v"(w1), "+v"(w3));
                union { u32 u[4]; bf16x8 v; } pu;
                pu.u[0] = w0; pu.u[1] = w1; pu.u[2] = w2; pu.u[3] = w3;
                bf16x8 v0 = *(const bf16x8*)(&Vt[cur][q31][c*16 + h*8]);
                bf16x8 v1 = *(const bf16x8*)(&Vt[cur][32 + q31][c*16 + h*8]);
                oacc0 = __builtin_amdgcn_mfma_f32_32x32x16_bf16(v0, pu.v, oacc0, 0, 0, 0);
                oacc1 = __builtin_amdgcn_mfma_f32_32x32x16_bf16(v1, pu.v, oacc1, 0, 0, 0);
            }
            __builtin_amdgcn_s_setprio(0);
        }

        // ---- write prefetched tile to the other buffer; one barrier/tile ----
        if (pf_on) {
            *(uint4*)(&Kl[cur^1][krow][kd]) = make_uint4(
                cvt2(kpf0.x,kpf0.y), cvt2(kpf0.z,kpf0.w),
                cvt2(kpf1.x,kpf1.y), cvt2(kpf1.z,kpf1.w));
            Vt[cur^1][vd0+0][vrow] = cvt1(vpf0.x); Vt[cur^1][vd0+1][vrow] = cvt1(vpf0.y);
            Vt[cur^1][vd0+2][vrow] = cvt1(vpf0.z); Vt[cur^1][vd0+3][vrow] = cvt1(vpf0.w);
            Vt[cur^1][vd0+4][vrow] = cvt1(vpf1.x); Vt[cur^1][vd0+5][vrow] = cvt1(vpf1.y);
            Vt[cur^1][vd0+6][vrow] = cvt1(vpf1.z); Vt[cur^1][vd0+7][vrow] = cvt1(vpf1.w);
            kpt += (size_t)KVBLK * KVSTR;
            vpt += (size_t)KVBLK * KVSTR;
            __syncthreads();
            cur ^= 1;
        }
    }

    // ---- epilogue: combine halves' l, normalize, store O^T (float4) ----
    l_p += __shfl_xor(l_p, 32);
    const float inv = 1.0f / l_p;
    #pragma unroll
    for (int k = 0; k < 4; ++k) {
        float4 o;
        o.x = oacc0[4*k+0]*inv; o.y = oacc0[4*k+1]*inv;
        o.z = oacc0[4*k+2]*inv; o.w = oacc0[4*k+3]*inv;
        *(float4*)(ob + 8*k + 4*h) = o;
        o.x = oacc1[4*k+0]*inv; o.y = oacc1[4*k+1]*inv;
        o.z = oacc1[4*k+2]*inv; o.w = oacc1[4*k+3]*inv;
        *(float4*)(ob + 32 + 8*k + 4*h) = o;
    }
}

extern "C" void kernel_launch(void* const* d_in, const int* in_sizes, int n_in,
                              void* d_out, int out_size, void* d_ws, size_t ws_size,
                              hipStream_t stream) {
    const float* Q = (const float*)d_in[0];
    const float* K = (const float*)d_in[1];
    const float* V = (const float*)d_in[2];
    // d_in[3] (tril mask) computed analytically, never read.
    float* O = (float*)d_out;
    gqa_fwd_kernel<<<dim3(256), dim3(512), 0, stream>>>(Q, K, V, O);
}